// Round 1
// baseline (186.598 us; speedup 1.0000x reference)
//
#include <hip/hip_runtime.h>

// ---------------- problem constants ----------------
#define HH 16
#define DD 64
#define SQ 1024          // queries
#define LW 8192          // attention window (keys)
#define OLDK 7168        // old (already-RoPE'd) keys in window
#define CACHE_BASE 2560  // cache row index of window position 0
#define SFRAME 9728      // START_FRAME
#define KSPLIT 4
#define KPER (LW / KSPLIT)   // 2048 keys per split
#define NSTEP (KPER / 64)    // 32 K-steps of 64 keys

// ws layout (bytes)
#define KB_OFF 0u                    // bf16 Kb[h][8192][64]   = 16 MiB
#define VT_OFF 16777216u             // bf16 Vt[h][64][8192]   = 16 MiB
#define QB_OFF 33554432u             // bf16 Qb[h][1024][64]   =  2 MiB
#define OP_OFF 35651584u             // f32 Op[ks][h][1024][64]= 16 MiB
#define LP_OFF 52428800u             // f32 Lp[ks][h][1024]    = 256 KiB
// total 52,690,944 + 262,144 = ~50.5 MiB of ws

typedef __bf16 bf16x8 __attribute__((ext_vector_type(8)));
typedef float floatx16 __attribute__((ext_vector_type(16)));

__device__ __forceinline__ unsigned short f2bf(float f) {
  unsigned u = __builtin_bit_cast(unsigned, f);
  u += 0x7fffu + ((u >> 16) & 1u);           // RNE
  return (unsigned short)(u >> 16);
}

__device__ __forceinline__ float fast_exp2(float x) {
#if __has_builtin(__builtin_amdgcn_exp2f)
  return __builtin_amdgcn_exp2f(x);
#else
  return __builtin_exp2f(x);
#endif
}

__device__ __forceinline__ void async16(void* lds, const void* g) {
  __builtin_amdgcn_global_load_lds((__attribute__((address_space(1))) void*)(g),
                                   (__attribute__((address_space(3))) void*)(lds),
                                   16, 0, 0);
}

// ---------------- prepass: build bf16 Kb / Vt(transposed) / Qb(rope*scale) ----
__global__ __launch_bounds__(256) void prepass(
    const float* __restrict__ qin, const float* __restrict__ kin,
    const float* __restrict__ vin, const float* __restrict__ ck,
    const float* __restrict__ cv, const float* __restrict__ fc,
    const float* __restrict__ fs, unsigned short* __restrict__ Kb,
    unsigned short* __restrict__ Vt, unsigned short* __restrict__ Qb) {
  int b = blockIdx.x, t = threadIdx.x;
  if (b < 2048) {
    // V transpose: 64kk x 64d tile -> Vt[h][d][kk]
    __shared__ float tl[64 * 65];
    int h = b >> 7, kk0 = (b & 127) * 64;
    int col = t & 63, rb = t >> 6;
#pragma unroll
    for (int i = 0; i < 16; i++) {
      int r = i * 4 + rb;
      int kk = kk0 + r;
      float val = (kk < OLDK) ? cv[(CACHE_BASE + kk) * (HH * DD) + h * DD + col]
                              : vin[(kk - OLDK) * (HH * DD) + h * DD + col];
      tl[r * 65 + col] = val;
    }
    __syncthreads();
#pragma unroll
    for (int i = 0; i < 16; i++) {
      int d = i * 4 + rb;
      Vt[(h * DD + d) * LW + kk0 + col] = f2bf(tl[col * 65 + d]);
    }
  } else if (b < 9216) {
    // K copy (old keys, already RoPE'd in cache): [kk][h][d] -> Kb[h][kk][d]
    int b1 = b - 2048;
    int h = b1 / 448, g = b1 % 448;
    int kk = g * 16 + (t >> 4);
    int lane = t & 15;
    float4 val = *(const float4*)(ck + (CACHE_BASE + kk) * (HH * DD) + h * DD + lane * 4);
    ushort4 o;
    o.x = f2bf(val.x); o.y = f2bf(val.y); o.z = f2bf(val.z); o.w = f2bf(val.w);
    *(ushort4*)(Kb + (h * LW + kk) * DD + lane * 4) = o;
  } else if (b < 11264) {
    // K rope (new keys)
    int b2 = b - 9216;
    int rh = b2 * 8 + (t >> 5);
    int s = rh >> 4, h = rh & 15, i = t & 31;
    float2 x = *(const float2*)(kin + s * (HH * DD) + h * DD + 2 * i);
    float c = fc[(SFRAME + s) * DD + 2 * i];
    float sn = fs[(SFRAME + s) * DD + 2 * i];
    ushort2 o;
    o.x = f2bf(x.x * c - x.y * sn);
    o.y = f2bf(x.y * c + x.x * sn);
    *(ushort2*)(Kb + (h * LW + OLDK + s) * DD + 2 * i) = o;
  } else {
    // Q rope + fold (1/sqrt(D)) * log2(e) so scores feed exp2 directly
    int b3 = b - 11264;
    int rh = b3 * 8 + (t >> 5);
    int s = rh >> 4, h = rh & 15, i = t & 31;
    const float SC = 0.18033688011112042f;  // 0.125 * log2(e)
    float2 x = *(const float2*)(qin + s * (HH * DD) + h * DD + 2 * i);
    float c = fc[(SFRAME + s) * DD + 2 * i];
    float sn = fs[(SFRAME + s) * DD + 2 * i];
    ushort2 o;
    o.x = f2bf((x.x * c - x.y * sn) * SC);
    o.y = f2bf((x.y * c + x.x * sn) * SC);
    *(ushort2*)(Qb + (h * SQ + s) * DD + 2 * i) = o;
  }
}

// ---------------- flash attention (no-max exp2 softmax, K-split) -------------
// grid: bid = g + 64*qb ; g = h + 16*ks (same (h,ks) share XCD via bid%8)
__global__ __launch_bounds__(256) void attn(
    const unsigned short* __restrict__ Kb, const unsigned short* __restrict__ Vt,
    const unsigned short* __restrict__ Qb, float* __restrict__ Op,
    float* __restrict__ Lp) {
  __shared__ __align__(16) unsigned char sK[8192];           // 64kk x 64d bf16 (swizzled granules)
  __shared__ __align__(16) unsigned char sV[8192];           // 64d x 64kk bf16 (swizzled granules)
  __shared__ __align__(16) unsigned char sP[4 * 32 * 144];   // per-wave P[q][kk], 144B rows

  int bid = blockIdx.x;
  int g = bid & 63, qb = bid >> 6;
  int h = g & 15, ks = g >> 4;
  int t = threadIdx.x;
  int w = t >> 6, lane = t & 63;
  int l31 = lane & 31, e = lane >> 5;
  int sw = l31 & 7;
  int qrow = qb * 128 + w * 32 + l31;

  // hoisted Q B-fragments: B[k=d][n=q], lane holds n=lane&31, k=8e+j
  bf16x8 qf[4];
  const unsigned short* qptr = Qb + (h * SQ + qrow) * DD + 8 * e;
#pragma unroll
  for (int c = 0; c < 4; c++) qf[c] = *(const bf16x8*)(qptr + 16 * c);

  floatx16 oA, oB;
#pragma unroll
  for (int i = 0; i < 16; i++) { oA[i] = 0.f; oB[i] = 0.f; }
  float lsum = 0.f;

  const unsigned short* KbH = Kb + h * (LW * DD);
  const unsigned short* VtH = Vt + h * (DD * LW);
  int kkBase = ks * KPER;
  unsigned char* prow = sP + (w * 32 + l31) * 144;

  for (int st = 0; st < NSTEP; st++) {
    int kk0 = kkBase + st * 64;
    __syncthreads();
    // stage K-tile and V^T-tile, XOR-swizzled 16B granules
#pragma unroll
    for (int hf = 0; hf < 2; hf++) {
      int gi = w * 128 + hf * 64 + lane;
      int rr = gi >> 3;                       // kk for K, d for V
      int bs = (gi & 7) ^ (rr & 7);           // swizzled granule column
      async16(sK + gi * 16, KbH + (kk0 + rr) * DD + bs * 8);
      async16(sV + gi * 16, VtH + rr * LW + kk0 + bs * 8);
    }
    __syncthreads();

    // S^T[kk][q] = sum_d K[kk][d] * Q[q][d]  (scores pre-scaled via Qb)
    floatx16 stA, stB;
#pragma unroll
    for (int i = 0; i < 16; i++) { stA[i] = 0.f; stB[i] = 0.f; }
#pragma unroll
    for (int c = 0; c < 4; c++) {
      int gsl = (2 * c + e) ^ sw;
      bf16x8 ka = *(const bf16x8*)(sK + (l31 * 8 + gsl) * 16);
      bf16x8 kb = *(const bf16x8*)(sK + ((l31 + 32) * 8 + gsl) * 16);
      stA = __builtin_amdgcn_mfma_f32_32x32x16_bf16(ka, qf[c], stA, 0, 0, 0);
      stB = __builtin_amdgcn_mfma_f32_32x32x16_bf16(kb, qf[c], stB, 0, 0, 0);
    }

    // P = exp2(S'); accumulate row-sum; pack bf16 (round-half-up via +0x8000)
    float ps = 0.f;
#pragma unroll
    for (int i = 0; i < 16; i++) { stA[i] = fast_exp2(stA[i]); ps += stA[i]; }
#pragma unroll
    for (int i = 0; i < 16; i++) { stB[i] = fast_exp2(stB[i]); ps += stB[i]; }
    lsum += ps;

#pragma unroll
    for (int mt = 0; mt < 2; mt++) {
#pragma unroll
      for (int t4 = 0; t4 < 4; t4++) {
        float v0 = mt ? stB[4 * t4 + 0] : stA[4 * t4 + 0];
        float v1 = mt ? stB[4 * t4 + 1] : stA[4 * t4 + 1];
        float v2 = mt ? stB[4 * t4 + 2] : stA[4 * t4 + 2];
        float v3 = mt ? stB[4 * t4 + 3] : stA[4 * t4 + 3];
        unsigned u0 = __builtin_bit_cast(unsigned, v0) + 0x8000u;
        unsigned u1 = __builtin_bit_cast(unsigned, v1) + 0x8000u;
        unsigned u2 = __builtin_bit_cast(unsigned, v2) + 0x8000u;
        unsigned u3 = __builtin_bit_cast(unsigned, v3) + 0x8000u;
        uint2 pk;
        pk.x = __builtin_amdgcn_perm(u1, u0, 0x07060302);
        pk.y = __builtin_amdgcn_perm(u3, u2, 0x07060302);
        // kk offsets {32mt+8t4+4e + 0..3} of row q
        *(uint2*)(prow + 64 * mt + 16 * t4 + 8 * e) = pk;
      }
    }

    // O^T[d][q] += sum_kk V^T[d][kk] * P[q][kk]
#pragma unroll
    for (int kc = 0; kc < 4; kc++) {
      int gsl = (2 * kc + e) ^ sw;
      bf16x8 va = *(const bf16x8*)(sV + (l31 * 8 + gsl) * 16);
      bf16x8 vb = *(const bf16x8*)(sV + ((l31 + 32) * 8 + gsl) * 16);
      bf16x8 pf = *(const bf16x8*)(prow + 32 * kc + 16 * e);
      oA = __builtin_amdgcn_mfma_f32_32x32x16_bf16(va, pf, oA, 0, 0, 0);
      oB = __builtin_amdgcn_mfma_f32_32x32x16_bf16(vb, pf, oB, 0, 0, 0);
    }
  }

  // epilogue: store split numerator + denominator
  lsum += __shfl_xor(lsum, 32, 64);
  float* op = Op + (((ks * 16 + h) * SQ) + qrow) * DD;
#pragma unroll
  for (int t4 = 0; t4 < 4; t4++) {
    float4 a, b;
    a.x = oA[4 * t4 + 0]; a.y = oA[4 * t4 + 1]; a.z = oA[4 * t4 + 2]; a.w = oA[4 * t4 + 3];
    b.x = oB[4 * t4 + 0]; b.y = oB[4 * t4 + 1]; b.z = oB[4 * t4 + 2]; b.w = oB[4 * t4 + 3];
    *(float4*)(op + 8 * t4 + 4 * e) = a;         // d0 = 8t4+4e
    *(float4*)(op + 32 + 8 * t4 + 4 * e) = b;    // d0 = 32+8t4+4e
  }
  if (e == 0) Lp[(ks * 16 + h) * SQ + qrow] = lsum;
}

// ---------------- combine splits ----------------
__global__ __launch_bounds__(256) void combine(const float* __restrict__ Op,
                                               const float* __restrict__ Lp,
                                               float* __restrict__ out) {
  int idx = blockIdx.x * 256 + threadIdx.x;
  int d = idx & 63, q = (idx >> 6) & 1023, h = idx >> 16;
  float num = 0.f, den = 0.f;
#pragma unroll
  for (int s = 0; s < KSPLIT; s++) {
    int row = (s * 16 + h) * SQ + q;
    num += Op[row * DD + d];
    den += Lp[row];
  }
  out[q * (HH * DD) + h * DD + d] = num / den;
}

extern "C" void kernel_launch(void* const* d_in, const int* in_sizes, int n_in,
                              void* d_out, int out_size, void* d_ws, size_t ws_size,
                              hipStream_t stream) {
  const float* q  = (const float*)d_in[0];
  const float* k  = (const float*)d_in[1];
  const float* v  = (const float*)d_in[2];
  const float* ck = (const float*)d_in[3];
  const float* cv = (const float*)d_in[4];
  const float* fc = (const float*)d_in[5];
  const float* fs = (const float*)d_in[6];
  float* out = (float*)d_out;
  char* ws = (char*)d_ws;

  unsigned short* Kb = (unsigned short*)(ws + KB_OFF);
  unsigned short* Vt = (unsigned short*)(ws + VT_OFF);
  unsigned short* Qb = (unsigned short*)(ws + QB_OFF);
  float* Op = (float*)(ws + OP_OFF);
  float* Lp = (float*)(ws + LP_OFF);

  prepass<<<13312, 256, 0, stream>>>(q, k, v, ck, cv, fc, fs, Kb, Vt, Qb);
  attn<<<512, 256, 0, stream>>>(Kb, Vt, Qb, Op, Lp);
  combine<<<4096, 256, 0, stream>>>(Op, Lp, out);
}